// Round 8
// baseline (416.355 us; speedup 1.0000x reference)
//
#include <hip/hip_runtime.h>
#include <hip/hip_bf16.h>
#include <type_traits>

// MHA forward: B=4, L=2048, D=1024, H=16, dk=64.
// Inputs f32 (+ int32 mask), OUTPUT f32. Internals bf16 MFMA, fp32 accum.
// R14: R13 + double-buffered K/V prefetch with __syncthreads-ONLY sync.
// Per tile: issue DMA for kt+1 into buf[cur^1], compute on buf[cur], one
// __syncthreads (compiler-guaranteed vmcnt0+lgkm0+fence+barrier), swap.
// Race-free by construction: barrier at end of t-1 drains all reads of
// buf[cur^1] before any wave issues t's prefetch into it (this is what
// R12's raw s_barrier did NOT guarantee -- s_barrier is not an IR memory
// fence, so a ds_read could be scheduled into the prefetch window).
// Kept from R13: zero-shuffle PV (sigma-permuted QK^T A-rows), conflict-free
// XOR key f(r)=(r&3)|((r>>1)&4), shift-free softmax (scale*log2e folded into
// Q projection), hw cvt_pk_bf16 pack, 8-wave/512-thr blocks, lb(512,2).

typedef __hip_bfloat16 bf16;
typedef __attribute__((ext_vector_type(8))) short s8;   // 8 bf16 (MFMA A/B frag)
typedef __attribute__((ext_vector_type(4))) short s4;   // 4 bf16 = 8B
typedef __attribute__((ext_vector_type(4))) float f4;   // MFMA C/D frag

constexpr int Bb = 4, Ls = 2048, Dd = 1024, Hh = 16, DK = 64;
constexpr int BHn = Bb * Hh;          // 64
constexpr int Mrows = Bb * Ls;        // 8192

typedef const __attribute__((address_space(1))) unsigned int* gas_t;
typedef __attribute__((address_space(3))) unsigned int* las_t;
__device__ __forceinline__ void dma16(const void* g, void* l) {
    __builtin_amdgcn_global_load_lds((gas_t)g, (las_t)l, 16, 0, 0);
}

__device__ __forceinline__ s8 ld8(const float* __restrict__ p) {
    const float4 a = *(const float4*)p;
    const float4 b = *(const float4*)(p + 4);
    union { bf16 h[8]; s8 v; } u;
    u.h[0] = __float2bfloat16(a.x); u.h[1] = __float2bfloat16(a.y);
    u.h[2] = __float2bfloat16(a.z); u.h[3] = __float2bfloat16(a.w);
    u.h[4] = __float2bfloat16(b.x); u.h[5] = __float2bfloat16(b.y);
    u.h[6] = __float2bfloat16(b.z); u.h[7] = __float2bfloat16(b.w);
    return u.v;
}
__device__ __forceinline__ void st1(bf16* p, float v)  { *p = __float2bfloat16(v); }
__device__ __forceinline__ void st1(float* p, float v) { *p = v; }

// ---------------- f32 -> bf16 convert (vectorized) ----------------
__global__ __launch_bounds__(256) void conv_bf16(
    const float* __restrict__ in, bf16* __restrict__ out, int n8)
{
    const int i = blockIdx.x * 256 + threadIdx.x;
    if (i < n8) *(s8*)&out[(size_t)i * 8] = ld8(in + (size_t)i * 8);
}

// ---------------- NT GEMM: out[m][n] = (sum_k A[m][k]*W[n][k] + bias[n]) * osc ----------------
// MODE 0: out row-major [M][N] (f32 d_out) | MODE 1: headed [bh][l][d] | MODE 2: [bh][d][l]
template<int MODE, typename WT, typename OT>
__global__ __launch_bounds__(256) void gemm_nt(
    const bf16* __restrict__ A, const WT* __restrict__ W,
    const float* __restrict__ bias, OT* __restrict__ out,
    int M, int N, int K, float osc)
{
    __shared__ __align__(16) bf16 lA[128 * 32];
    __shared__ __align__(16) bf16 lB[128 * 32];
    const int tid  = threadIdx.x;
    const int wave = tid >> 6, lane = tid & 63;
    const int qd = lane >> 4, lr = lane & 15;
    const int wm = (wave & 1) * 64, wn = (wave >> 1) * 64;
    const int row0 = blockIdx.x * 128, col0 = blockIdx.y * 128;

    f4 acc[4][4] = {};

    // f32-W staging coords (only used when WT==float)
    const int c0 = tid, c1 = tid + 256;
    const int wr0 = c0 >> 2, wk0 = (c0 & 3) * 8;
    const int wr1 = c1 >> 2, wk1 = (c1 & 3) * 8;

    for (int kt = 0; kt < K; kt += 32) {
#pragma unroll
        for (int r = 0; r < 2; r++) {           // A via direct-to-LDS DMA
            const int s = r * 256 + tid;
            const int row = s >> 2, c = s & 3;
            dma16(A + (size_t)(row0 + row) * K + kt + c * 8, &lA[s * 8]);
        }
        if constexpr (std::is_same<WT, bf16>::value) {
#pragma unroll
            for (int r = 0; r < 2; r++) {
                const int s = r * 256 + tid;
                const int row = s >> 2, c = s & 3;
                dma16(W + (size_t)(col0 + row) * K + kt + c * 8, &lB[s * 8]);
            }
        } else {
            *(s8*)&lB[c0 * 8] = ld8(W + (size_t)(col0 + wr0) * K + kt + wk0);
            *(s8*)&lB[c1 * 8] = ld8(W + (size_t)(col0 + wr1) * K + kt + wk1);
        }
        __syncthreads();
        s8 af[4], bfm[4];
#pragma unroll
        for (int i = 0; i < 4; i++) af[i]  = *(const s8*)&lA[(wm + i * 16 + lr) * 32 + qd * 8];
#pragma unroll
        for (int j = 0; j < 4; j++) bfm[j] = *(const s8*)&lB[(wn + j * 16 + lr) * 32 + qd * 8];
#pragma unroll
        for (int i = 0; i < 4; i++)
#pragma unroll
            for (int j = 0; j < 4; j++)
                acc[i][j] = __builtin_amdgcn_mfma_f32_16x16x32_bf16(af[i], bfm[j], acc[i][j], 0, 0, 0);
        __syncthreads();
    }

    // epilogue: C/D layout col=lane&15, row=(lane>>4)*4+reg
#pragma unroll
    for (int j = 0; j < 4; j++) {
        const int colg = col0 + wn + j * 16 + lr;
        const float bv = bias[colg];
#pragma unroll
        for (int i = 0; i < 4; i++) {
            const int rowb = row0 + wm + i * 16 + qd * 4;
            if (MODE == 2) {
                const int b = rowb >> 11, l = rowb & (Ls - 1);
                const int h = colg >> 6, d = colg & (DK - 1);
                union { bf16 h4[4]; s4 v; } u;
#pragma unroll
                for (int ri = 0; ri < 4; ri++)
                    u.h4[ri] = __float2bfloat16((acc[i][j][ri] + bv) * osc);
                *(s4*)&((bf16*)out)[(((size_t)(b * Hh + h) * DK) + d) * Ls + l] = u.v;
            } else {
#pragma unroll
                for (int ri = 0; ri < 4; ri++) {
                    const int rowg = rowb + ri;
                    const float v = (acc[i][j][ri] + bv) * osc;
                    size_t idx;
                    if (MODE == 0) {
                        idx = (size_t)rowg * N + colg;
                    } else {
                        const int b = rowg >> 11, l = rowg & (Ls - 1);
                        const int h = colg >> 6, d = colg & (DK - 1);
                        idx = (((size_t)(b * Hh + h) * Ls) + l) * DK + d;
                    }
                    st1(&out[idx], v);
                }
            }
        }
    }
}

// ---------------- mask bit-pack ----------------
__global__ __launch_bounds__(256) void pack_mask(
    const int* __restrict__ m, unsigned long long* __restrict__ bits)
{
    const int g = blockIdx.x * 256 + threadIdx.x;
    const unsigned long long b = __ballot(m[g] != 0);
    if ((threadIdx.x & 63) == 0) bits[g >> 6] = b;
}

// ---------------- flash attention, S^T orientation, zero-shuffle PV ----------------
// grid: BH*(L/128); block 512 = 8 waves; wave owns 16 q (cols of S^T), full dk=64.
// All 8 waves share one 64x64 K/V tile pair, double-buffered (32 KB LDS),
// prefetch + one __syncthreads per tile.
// LDS tiles XOR-swizzled in 16B chunks with key f(r) = (r&3)|((r>>1)&4):
// (row r, chunk c) stored at [(r*8 + (c ^ f(r)))*8].
// QK^T A-rows are fed through permutation sigma:
//   MFMA mt, row r  <-  k = 32*(mt>>1) + 8*(r>>2) + 4*(mt&1) + (r&3)
// so each lane's C-fragment k-set equals its PV B-frag k-set in register
// order -> PV B-frag is a plain concat of the lane's own pk words.
__global__ __launch_bounds__(512, 2) void attn(
    const bf16* __restrict__ Q, const bf16* __restrict__ K,
    const bf16* __restrict__ Vt, const unsigned long long* __restrict__ mbits,
    bf16* __restrict__ X)
{
    __shared__ __align__(16) bf16 lK[2][64 * 64];   // [buf][k][d], swizzled
    __shared__ __align__(16) bf16 lV[2][64 * 64];   // [buf][d][k], swizzled

    const int blk = blockIdx.x;
    const int bh = blk >> 4;
    const int q0 = (blk & 15) * 128;
    const int tid = threadIdx.x;
    const int wave = tid >> 6, lane = tid & 63;
    const int qd = lane >> 4, lr = lane & 15;
    const int qw0 = q0 + wave * 16;

    const bf16* Qb = Q  + (size_t)bh * Ls * DK;
    const bf16* Kb = K  + (size_t)bh * Ls * DK;
    const bf16* Vb = Vt + (size_t)bh * DK * Ls;

    // Q B-frags straight from global: lane lr -> q, elems qd*8+j -> d
    const s8 bq0 = *(const s8*)(Qb + (size_t)(qw0 + lr) * DK + qd * 8);
    const s8 bq1 = *(const s8*)(Qb + (size_t)(qw0 + lr) * DK + 32 + qd * 8);

    f4 o[4] = {};                      // O^T C-frags: row=d-in-tile, col=q
    float lp = 0.f;                    // per-lane l partial (replicated over qd)

    // staging: 512 threads cover the 512 16B chunks of each 8KB tile
    const int srow = tid >> 3, scs = tid & 7;
    const int sc = scs ^ ((srow & 3) | ((srow >> 1) & 4));
    const bf16* gK = Kb + (size_t)srow * DK + sc * 8;
    const bf16* gV = Vb + (size_t)srow * Ls + sc * 8;

    const size_t mrow = (size_t)(qw0 + lr) * (Ls / 64);

    // prologue: stage tile 0 into buf 0
    dma16(gK, &lK[0][tid * 8]);
    dma16(gV, &lV[0][tid * 8]);
    unsigned long long wcur = mbits[mrow];
    __syncthreads();   // tile 0 landed (vmcnt0+lgkm0+fence+barrier)

    int cur = 0;
    for (int kt = 0; kt < Ls / 64; ++kt) {
        // prefetch tile kt+1 into the other buffer; overlaps with compute.
        // Safe: the __syncthreads at end of kt-1 guaranteed all waves finished
        // reading buf[cur^1].
        unsigned long long wnext = 0;
        if (kt + 1 < Ls / 64) {
            const int nb = cur ^ 1;
            dma16(gK + (size_t)(kt + 1) * 64 * DK, &lK[nb][tid * 8]);
            dma16(gV + (size_t)(kt + 1) * 64,      &lV[nb][tid * 8]);
            wnext = mbits[mrow + kt + 1];
        }

        // S^T = K_tile . Q^T with sigma-permuted A-rows:
        //   st[mt][ri] = S^T[k = 32*(mt>>1) + 8*qd + 4*(mt&1) + ri][q = lr]
        f4 st[4];
        __builtin_amdgcn_s_setprio(1);
#pragma unroll
        for (int mt = 0; mt < 4; mt++) {
            const int rk = 32 * (mt >> 1) + 8 * (lr >> 2) + 4 * (mt & 1) + (lr & 3);
            const int fr = (rk & 3) | ((rk >> 1) & 4);
            const s8 ak0 = *(const s8*)&lK[cur][(rk * 8 + ((qd)     ^ fr)) * 8];
            const s8 ak1 = *(const s8*)&lK[cur][(rk * 8 + ((4 + qd) ^ fr)) * 8];
            f4 z = {};
            z = __builtin_amdgcn_mfma_f32_16x16x32_bf16(ak0, bq0, z, 0, 0, 0);
            z = __builtin_amdgcn_mfma_f32_16x16x32_bf16(ak1, bq1, z, 0, 0, 0);
            st[mt] = z;
        }
        __builtin_amdgcn_s_setprio(0);

        // mask (fast path: whole wave all-ones -> nothing to do)
        if (__ballot(wcur == ~0ULL) != ~0ULL) {
#pragma unroll
            for (int mt = 0; mt < 4; mt++)
#pragma unroll
                for (int ri = 0; ri < 4; ri++) {
                    const int kbit = 32 * (mt >> 1) + 8 * qd + 4 * (mt & 1) + ri;
                    if (!((wcur >> kbit) & 1ULL)) st[mt][ri] = -1e9f;
                }
        }

        // shift-free softmax: P = exp2(st), accumulate l partial
        unsigned pk[4][2];              // bf16-pair packs of P^T values (ri pairs)
#pragma unroll
        for (int mt = 0; mt < 4; mt++) {
#pragma unroll
            for (int u = 0; u < 2; u++) {
                const float p0 = __builtin_amdgcn_exp2f(st[mt][2 * u]);
                const float p1 = __builtin_amdgcn_exp2f(st[mt][2 * u + 1]);
                lp += p0 + p1;
                unsigned r;
                asm("v_cvt_pk_bf16_f32 %0, %1, %2" : "=v"(r) : "v"(p0), "v"(p1));
                pk[mt][u] = r;
            }
        }

        // PV: O^T += V^T . P^T ; B-frag is the lane's own pk words (sigma made
        // the C->B k-sets match): j=0..3 <- mt=2h, j=4..7 <- mt=2h+1.
#pragma unroll
        for (int h = 0; h < 2; h++) {
            union { unsigned u[4]; s8 v; } bp;
            bp.u[0] = pk[2 * h][0];
            bp.u[1] = pk[2 * h][1];
            bp.u[2] = pk[2 * h + 1][0];
            bp.u[3] = pk[2 * h + 1][1];
            __builtin_amdgcn_s_setprio(1);
#pragma unroll
            for (int dt = 0; dt < 4; dt++) {
                const int rowd = dt * 16 + lr;
                const int fv = (rowd & 3) | ((rowd >> 1) & 4);
                const s8 av = *(const s8*)&lV[cur][(rowd * 8 + ((h * 4 + qd) ^ fv)) * 8];
                o[dt] = __builtin_amdgcn_mfma_f32_16x16x32_bf16(av, bp.v, o[dt], 0, 0, 0);
            }
            __builtin_amdgcn_s_setprio(0);
        }

        // one barrier per tile: drains prefetch DMA (vmcnt) + my LDS reads
        // (lgkm) + synchronizes all waves, with compiler-enforced ordering.
        __syncthreads();
        cur ^= 1;
        wcur = wnext;
    }

    // epilogue: reduce l across qd groups, then X[b][q][head*64 + d] = O^T[d][q] / l
    float lsum = lp;
    lsum += __shfl_xor(lsum, 16, 64);
    lsum += __shfl_xor(lsum, 32, 64);
    const int b = bh >> 4, head = bh & 15;
    const float inv = 1.f / lsum;
    const int qrow = qw0 + lr;
#pragma unroll
    for (int dt = 0; dt < 4; dt++) {
        union { bf16 h4[4]; s4 v; } u;
#pragma unroll
        for (int ri = 0; ri < 4; ri++)
            u.h4[ri] = __float2bfloat16(o[dt][ri] * inv);
        *(s4*)&X[((size_t)(b * Ls + qrow)) * Dd + head * 64 + dt * 16 + qd * 4] = u.v;
    }
}

extern "C" void kernel_launch(void* const* d_in, const int* in_sizes, int n_in,
                              void* d_out, int out_size, void* d_ws, size_t ws_size,
                              hipStream_t stream) {
    const float* q_in = (const float*)d_in[0];
    const float* k_in = (const float*)d_in[1];
    const float* v_in = (const float*)d_in[2];
    const int*   mask = (const int*)d_in[3];
    const float* Wq = (const float*)d_in[4];  const float* bq = (const float*)d_in[5];
    const float* Wk = (const float*)d_in[6];  const float* bk = (const float*)d_in[7];
    const float* Wv = (const float*)d_in[8];  const float* bv = (const float*)d_in[9];
    const float* Wo = (const float*)d_in[10]; const float* bo = (const float*)d_in[11];
    float* out = (float*)d_out;

    char* ws = (char*)d_ws;
    const size_t sz = (size_t)BHn * Ls * DK * sizeof(bf16);   // 16.78 MB
    bf16* S0 = (bf16*)(ws);            // A-conv scratch, later Xp
    bf16* S1 = (bf16*)(ws + sz);       // Wv/Wk bf16 copies, later Qp
    bf16* S2 = (bf16*)(ws + 2 * sz);   // Kp, later Wo bf16 copy
    bf16* S3 = (bf16*)(ws + 3 * sz);   // Vt
    unsigned long long* mb = (unsigned long long*)(ws + 4 * sz);
    const int NW = Dd * Dd;            // 1M weight elems

    dim3 gg(Mrows / 128, Dd / 128);
    const int gA = (Mrows * Dd / 8 + 255) / 256;   // input conv grid
    const int gW = (NW / 8 + 255) / 256;           // weight conv grid

    // dk^-0.5 * log2(e), folded into the Q projection
    const float QSC = 0.125f * 1.44269504f;

    // V (transposed-out), K, then Q (runtime f32 W); weights ride in dead slots
    conv_bf16<<<gA, 256, 0, stream>>>(v_in, S0, Mrows * Dd / 8);
    conv_bf16<<<gW, 256, 0, stream>>>(Wv, S1, NW / 8);
    gemm_nt<2, bf16, bf16><<<gg, 256, 0, stream>>>(S0, S1, bv, S3, Mrows, Dd, Dd, 1.0f);

    conv_bf16<<<gA, 256, 0, stream>>>(k_in, S0, Mrows * Dd / 8);
    conv_bf16<<<gW, 256, 0, stream>>>(Wk, S1 + NW, NW / 8);
    gemm_nt<1, bf16, bf16><<<gg, 256, 0, stream>>>(S0, S1 + NW, bk, S2, Mrows, Dd, Dd, 1.0f);

    conv_bf16<<<gA, 256, 0, stream>>>(q_in, S0, Mrows * Dd / 8);
    gemm_nt<1, float, bf16><<<gg, 256, 0, stream>>>(S0, Wq, bq, S1, Mrows, Dd, Dd, QSC);

    pack_mask<<<(Ls * Ls) / 256, 256, 0, stream>>>(mask, mb);
    attn<<<BHn * (Ls / 128), 512, 0, stream>>>(S1, S2, S3, mb, S0);

    conv_bf16<<<gW, 256, 0, stream>>>(Wo, S2, NW / 8);   // Kp dead after attn
    gemm_nt<0, bf16, float><<<gg, 256, 0, stream>>>(S0, S2, bo, out, Mrows, Dd, Dd, 1.0f);
}

// Round 9
// 381.778 us; speedup vs baseline: 1.0906x; 1.0906x over previous
//
#include <hip/hip_runtime.h>
#include <hip/hip_bf16.h>
#include <type_traits>

// MHA forward: B=4, L=2048, D=1024, H=16, dk=64.
// Inputs f32 (+ int32 mask), OUTPUT f32. Internals bf16 MFMA, fp32 accum.
// R15: gemm_nt rebuilt with the attn lessons (attn itself unchanged from R14):
//  - double-buffered staging, __syncthreads-only sync (R14 pattern): prefetch
//    tile t+1 into buf^1, compute t, ONE barrier per tile.
//  - BK=64: 16 K-tiles instead of 32; 32 MFMAs between barriers.
//  - R13's conflict-free XOR swizzle f(r)=(r&3)|((r>>1)&4) on LDS tiles
//    (pre-swizzled DMA/ld8 source + swizzled ds_read), row stride 128B.
// Rationale: the 4 projection GEMMs are ~270 us of the 416 total; at 512
// blocks = 2 blocks/CU they are TLP-starved, so exposed DMA drain + LDS bank
// conflicts dominate (measured ~257 TF). Within-block pipelining + conflict-
// free reads is the same medicine that took attn 108->96.
// attn (R14): zero-shuffle PV, shift-free softmax, dbuf, 8-wave blocks.

typedef __hip_bfloat16 bf16;
typedef __attribute__((ext_vector_type(8))) short s8;   // 8 bf16 (MFMA A/B frag)
typedef __attribute__((ext_vector_type(4))) short s4;   // 4 bf16 = 8B
typedef __attribute__((ext_vector_type(4))) float f4;   // MFMA C/D frag

constexpr int Bb = 4, Ls = 2048, Dd = 1024, Hh = 16, DK = 64;
constexpr int BHn = Bb * Hh;          // 64
constexpr int Mrows = Bb * Ls;        // 8192

typedef const __attribute__((address_space(1))) unsigned int* gas_t;
typedef __attribute__((address_space(3))) unsigned int* las_t;
__device__ __forceinline__ void dma16(const void* g, void* l) {
    __builtin_amdgcn_global_load_lds((gas_t)g, (las_t)l, 16, 0, 0);
}

__device__ __forceinline__ s8 ld8(const float* __restrict__ p) {
    const float4 a = *(const float4*)p;
    const float4 b = *(const float4*)(p + 4);
    union { bf16 h[8]; s8 v; } u;
    u.h[0] = __float2bfloat16(a.x); u.h[1] = __float2bfloat16(a.y);
    u.h[2] = __float2bfloat16(a.z); u.h[3] = __float2bfloat16(a.w);
    u.h[4] = __float2bfloat16(b.x); u.h[5] = __float2bfloat16(b.y);
    u.h[6] = __float2bfloat16(b.z); u.h[7] = __float2bfloat16(b.w);
    return u.v;
}
__device__ __forceinline__ void st1(bf16* p, float v)  { *p = __float2bfloat16(v); }
__device__ __forceinline__ void st1(float* p, float v) { *p = v; }

// XOR swizzle key (R13-verified conflict-free for 128B-row-stride b128 reads)
__device__ __forceinline__ int fswz(int r) { return (r & 3) | ((r >> 1) & 4); }

// ---------------- f32 -> bf16 convert (vectorized) ----------------
__global__ __launch_bounds__(256) void conv_bf16(
    const float* __restrict__ in, bf16* __restrict__ out, int n8)
{
    const int i = blockIdx.x * 256 + threadIdx.x;
    if (i < n8) *(s8*)&out[(size_t)i * 8] = ld8(in + (size_t)i * 8);
}

// ---------------- NT GEMM: out[m][n] = (sum_k A[m][k]*W[n][k] + bias[n]) * osc ----------------
// MODE 0: out row-major [M][N] (f32 d_out) | MODE 1: headed [bh][l][d] | MODE 2: [bh][d][l]
// 128x128 tile, BK=64, double-buffered (64 KB LDS), one __syncthreads/tile.
// LDS layout: row r (128B = 8 chunks of 16B), chunk c stored at
// [(r*8 + (c ^ fswz(r)))*8]; DMA/ld8 source pre-swizzled to compensate.
template<int MODE, typename WT, typename OT>
__global__ __launch_bounds__(256) void gemm_nt(
    const bf16* __restrict__ A, const WT* __restrict__ W,
    const float* __restrict__ bias, OT* __restrict__ out,
    int M, int N, int K, float osc)
{
    __shared__ __align__(16) bf16 lA[2][128 * 64];
    __shared__ __align__(16) bf16 lB[2][128 * 64];
    const int tid  = threadIdx.x;
    const int wave = tid >> 6, lane = tid & 63;
    const int qd = lane >> 4, lr = lane & 15;
    const int wm = (wave & 1) * 64, wn = (wave >> 1) * 64;
    const int row0 = blockIdx.x * 128, col0 = blockIdx.y * 128;

    f4 acc[4][4] = {};

    const int NT = K >> 6;   // K-tiles of 64

    // prologue: stage tile 0 into buf 0
    {
#pragma unroll
        for (int r = 0; r < 4; r++) {
            const int s = r * 256 + tid;
            const int row = s >> 3;
            const int c = (s & 7) ^ fswz(row);
            dma16(A + (size_t)(row0 + row) * K + c * 8, &lA[0][s * 8]);
        }
#pragma unroll
        for (int r = 0; r < 4; r++) {
            const int s = r * 256 + tid;
            const int row = s >> 3;
            const int c = (s & 7) ^ fswz(row);
            if constexpr (std::is_same<WT, bf16>::value)
                dma16(W + (size_t)(col0 + row) * K + c * 8, &lB[0][s * 8]);
            else
                *(s8*)&lB[0][s * 8] = ld8(W + (size_t)(col0 + row) * K + c * 8);
        }
    }
    __syncthreads();

    int cur = 0;
    for (int t = 0; t < NT; ++t) {
        // prefetch tile t+1 into the other buffer (overlaps with compute)
        if (t + 1 < NT) {
            const int nb = cur ^ 1;
            const int kt = (t + 1) * 64;
#pragma unroll
            for (int r = 0; r < 4; r++) {
                const int s = r * 256 + tid;
                const int row = s >> 3;
                const int c = (s & 7) ^ fswz(row);
                dma16(A + (size_t)(row0 + row) * K + kt + c * 8, &lA[nb][s * 8]);
            }
#pragma unroll
            for (int r = 0; r < 4; r++) {
                const int s = r * 256 + tid;
                const int row = s >> 3;
                const int c = (s & 7) ^ fswz(row);
                if constexpr (std::is_same<WT, bf16>::value)
                    dma16(W + (size_t)(col0 + row) * K + kt + c * 8, &lB[nb][s * 8]);
                else
                    *(s8*)&lB[nb][s * 8] = ld8(W + (size_t)(col0 + row) * K + kt + c * 8);
            }
        }

        // compute on buf[cur]: 2 K-halves x 16 MFMA
#pragma unroll
        for (int kk = 0; kk < 2; kk++) {
            s8 af[4], bfm[4];
#pragma unroll
            for (int i = 0; i < 4; i++) {
                const int row = wm + i * 16 + lr;
                af[i] = *(const s8*)&lA[cur][(row * 8 + ((kk * 4 + qd) ^ fswz(row))) * 8];
            }
#pragma unroll
            for (int j = 0; j < 4; j++) {
                const int row = wn + j * 16 + lr;
                bfm[j] = *(const s8*)&lB[cur][(row * 8 + ((kk * 4 + qd) ^ fswz(row))) * 8];
            }
#pragma unroll
            for (int i = 0; i < 4; i++)
#pragma unroll
                for (int j = 0; j < 4; j++)
                    acc[i][j] = __builtin_amdgcn_mfma_f32_16x16x32_bf16(af[i], bfm[j], acc[i][j], 0, 0, 0);
        }

        __syncthreads();   // drains prefetch DMA + this tile's LDS reads
        cur ^= 1;
    }

    // epilogue: C/D layout col=lane&15, row=(lane>>4)*4+reg
#pragma unroll
    for (int j = 0; j < 4; j++) {
        const int colg = col0 + wn + j * 16 + lr;
        const float bv = bias[colg];
#pragma unroll
        for (int i = 0; i < 4; i++) {
            const int rowb = row0 + wm + i * 16 + qd * 4;
            if (MODE == 2) {
                const int b = rowb >> 11, l = rowb & (Ls - 1);
                const int h = colg >> 6, d = colg & (DK - 1);
                union { bf16 h4[4]; s4 v; } u;
#pragma unroll
                for (int ri = 0; ri < 4; ri++)
                    u.h4[ri] = __float2bfloat16((acc[i][j][ri] + bv) * osc);
                *(s4*)&((bf16*)out)[(((size_t)(b * Hh + h) * DK) + d) * Ls + l] = u.v;
            } else {
#pragma unroll
                for (int ri = 0; ri < 4; ri++) {
                    const int rowg = rowb + ri;
                    const float v = (acc[i][j][ri] + bv) * osc;
                    size_t idx;
                    if (MODE == 0) {
                        idx = (size_t)rowg * N + colg;
                    } else {
                        const int b = rowg >> 11, l = rowg & (Ls - 1);
                        const int h = colg >> 6, d = colg & (DK - 1);
                        idx = (((size_t)(b * Hh + h) * Ls) + l) * DK + d;
                    }
                    st1(&out[idx], v);
                }
            }
        }
    }
}

// ---------------- mask bit-pack ----------------
__global__ __launch_bounds__(256) void pack_mask(
    const int* __restrict__ m, unsigned long long* __restrict__ bits)
{
    const int g = blockIdx.x * 256 + threadIdx.x;
    const unsigned long long b = __ballot(m[g] != 0);
    if ((threadIdx.x & 63) == 0) bits[g >> 6] = b;
}

// ---------------- flash attention, S^T orientation, zero-shuffle PV ----------------
// (unchanged from R14)
__global__ __launch_bounds__(512, 2) void attn(
    const bf16* __restrict__ Q, const bf16* __restrict__ K,
    const bf16* __restrict__ Vt, const unsigned long long* __restrict__ mbits,
    bf16* __restrict__ X)
{
    __shared__ __align__(16) bf16 lK[2][64 * 64];   // [buf][k][d], swizzled
    __shared__ __align__(16) bf16 lV[2][64 * 64];   // [buf][d][k], swizzled

    const int blk = blockIdx.x;
    const int bh = blk >> 4;
    const int q0 = (blk & 15) * 128;
    const int tid = threadIdx.x;
    const int wave = tid >> 6, lane = tid & 63;
    const int qd = lane >> 4, lr = lane & 15;
    const int qw0 = q0 + wave * 16;

    const bf16* Qb = Q  + (size_t)bh * Ls * DK;
    const bf16* Kb = K  + (size_t)bh * Ls * DK;
    const bf16* Vb = Vt + (size_t)bh * DK * Ls;

    // Q B-frags straight from global: lane lr -> q, elems qd*8+j -> d
    const s8 bq0 = *(const s8*)(Qb + (size_t)(qw0 + lr) * DK + qd * 8);
    const s8 bq1 = *(const s8*)(Qb + (size_t)(qw0 + lr) * DK + 32 + qd * 8);

    f4 o[4] = {};                      // O^T C-frags: row=d-in-tile, col=q
    float lp = 0.f;                    // per-lane l partial (replicated over qd)

    // staging: 512 threads cover the 512 16B chunks of each 8KB tile
    const int srow = tid >> 3, scs = tid & 7;
    const int sc = scs ^ ((srow & 3) | ((srow >> 1) & 4));
    const bf16* gK = Kb + (size_t)srow * DK + sc * 8;
    const bf16* gV = Vb + (size_t)srow * Ls + sc * 8;

    const size_t mrow = (size_t)(qw0 + lr) * (Ls / 64);

    // prologue: stage tile 0 into buf 0
    dma16(gK, &lK[0][tid * 8]);
    dma16(gV, &lV[0][tid * 8]);
    unsigned long long wcur = mbits[mrow];
    __syncthreads();   // tile 0 landed (vmcnt0+lgkm0+fence+barrier)

    int cur = 0;
    for (int kt = 0; kt < Ls / 64; ++kt) {
        // prefetch tile kt+1 into the other buffer; overlaps with compute.
        unsigned long long wnext = 0;
        if (kt + 1 < Ls / 64) {
            const int nb = cur ^ 1;
            dma16(gK + (size_t)(kt + 1) * 64 * DK, &lK[nb][tid * 8]);
            dma16(gV + (size_t)(kt + 1) * 64,      &lV[nb][tid * 8]);
            wnext = mbits[mrow + kt + 1];
        }

        // S^T = K_tile . Q^T with sigma-permuted A-rows:
        //   st[mt][ri] = S^T[k = 32*(mt>>1) + 8*qd + 4*(mt&1) + ri][q = lr]
        f4 st[4];
        __builtin_amdgcn_s_setprio(1);
#pragma unroll
        for (int mt = 0; mt < 4; mt++) {
            const int rk = 32 * (mt >> 1) + 8 * (lr >> 2) + 4 * (mt & 1) + (lr & 3);
            const int fr = (rk & 3) | ((rk >> 1) & 4);
            const s8 ak0 = *(const s8*)&lK[cur][(rk * 8 + ((qd)     ^ fr)) * 8];
            const s8 ak1 = *(const s8*)&lK[cur][(rk * 8 + ((4 + qd) ^ fr)) * 8];
            f4 z = {};
            z = __builtin_amdgcn_mfma_f32_16x16x32_bf16(ak0, bq0, z, 0, 0, 0);
            z = __builtin_amdgcn_mfma_f32_16x16x32_bf16(ak1, bq1, z, 0, 0, 0);
            st[mt] = z;
        }
        __builtin_amdgcn_s_setprio(0);

        // mask (fast path: whole wave all-ones -> nothing to do)
        if (__ballot(wcur == ~0ULL) != ~0ULL) {
#pragma unroll
            for (int mt = 0; mt < 4; mt++)
#pragma unroll
                for (int ri = 0; ri < 4; ri++) {
                    const int kbit = 32 * (mt >> 1) + 8 * qd + 4 * (mt & 1) + ri;
                    if (!((wcur >> kbit) & 1ULL)) st[mt][ri] = -1e9f;
                }
        }

        // shift-free softmax: P = exp2(st), accumulate l partial
        unsigned pk[4][2];              // bf16-pair packs of P^T values (ri pairs)
#pragma unroll
        for (int mt = 0; mt < 4; mt++) {
#pragma unroll
            for (int u = 0; u < 2; u++) {
                const float p0 = __builtin_amdgcn_exp2f(st[mt][2 * u]);
                const float p1 = __builtin_amdgcn_exp2f(st[mt][2 * u + 1]);
                lp += p0 + p1;
                unsigned r;
                asm("v_cvt_pk_bf16_f32 %0, %1, %2" : "=v"(r) : "v"(p0), "v"(p1));
                pk[mt][u] = r;
            }
        }

        // PV: O^T += V^T . P^T ; B-frag is the lane's own pk words
#pragma unroll
        for (int h = 0; h < 2; h++) {
            union { unsigned u[4]; s8 v; } bp;
            bp.u[0] = pk[2 * h][0];
            bp.u[1] = pk[2 * h][1];
            bp.u[2] = pk[2 * h + 1][0];
            bp.u[3] = pk[2 * h + 1][1];
            __builtin_amdgcn_s_setprio(1);
#pragma unroll
            for (int dt = 0; dt < 4; dt++) {
                const int rowd = dt * 16 + lr;
                const int fv = (rowd & 3) | ((rowd >> 1) & 4);
                const s8 av = *(const s8*)&lV[cur][(rowd * 8 + ((h * 4 + qd) ^ fv)) * 8];
                o[dt] = __builtin_amdgcn_mfma_f32_16x16x32_bf16(av, bp.v, o[dt], 0, 0, 0);
            }
            __builtin_amdgcn_s_setprio(0);
        }

        // one barrier per tile: drains prefetch DMA + my LDS reads
        __syncthreads();
        cur ^= 1;
        wcur = wnext;
    }

    // epilogue: reduce l across qd groups, then X[b][q][head*64 + d] = O^T[d][q] / l
    float lsum = lp;
    lsum += __shfl_xor(lsum, 16, 64);
    lsum += __shfl_xor(lsum, 32, 64);
    const int b = bh >> 4, head = bh & 15;
    const float inv = 1.f / lsum;
    const int qrow = qw0 + lr;
#pragma unroll
    for (int dt = 0; dt < 4; dt++) {
        union { bf16 h4[4]; s4 v; } u;
#pragma unroll
        for (int ri = 0; ri < 4; ri++)
            u.h4[ri] = __float2bfloat16(o[dt][ri] * inv);
        *(s4*)&X[((size_t)(b * Ls + qrow)) * Dd + head * 64 + dt * 16 + qd * 4] = u.v;
    }
}

extern "C" void kernel_launch(void* const* d_in, const int* in_sizes, int n_in,
                              void* d_out, int out_size, void* d_ws, size_t ws_size,
                              hipStream_t stream) {
    const float* q_in = (const float*)d_in[0];
    const float* k_in = (const float*)d_in[1];
    const float* v_in = (const float*)d_in[2];
    const int*   mask = (const int*)d_in[3];
    const float* Wq = (const float*)d_in[4];  const float* bq = (const float*)d_in[5];
    const float* Wk = (const float*)d_in[6];  const float* bk = (const float*)d_in[7];
    const float* Wv = (const float*)d_in[8];  const float* bv = (const float*)d_in[9];
    const float* Wo = (const float*)d_in[10]; const float* bo = (const float*)d_in[11];
    float* out = (float*)d_out;

    char* ws = (char*)d_ws;
    const size_t sz = (size_t)BHn * Ls * DK * sizeof(bf16);   // 16.78 MB
    bf16* S0 = (bf16*)(ws);            // A-conv scratch, later Xp
    bf16* S1 = (bf16*)(ws + sz);       // Wv/Wk bf16 copies, later Qp
    bf16* S2 = (bf16*)(ws + 2 * sz);   // Kp, later Wo bf16 copy
    bf16* S3 = (bf16*)(ws + 3 * sz);   // Vt
    unsigned long long* mb = (unsigned long long*)(ws + 4 * sz);
    const int NW = Dd * Dd;            // 1M weight elems

    dim3 gg(Mrows / 128, Dd / 128);
    const int gA = (Mrows * Dd / 8 + 255) / 256;   // input conv grid
    const int gW = (NW / 8 + 255) / 256;           // weight conv grid

    // dk^-0.5 * log2(e), folded into the Q projection
    const float QSC = 0.125f * 1.44269504f;

    // V (transposed-out), K, then Q (runtime f32 W); weights ride in dead slots
    conv_bf16<<<gA, 256, 0, stream>>>(v_in, S0, Mrows * Dd / 8);
    conv_bf16<<<gW, 256, 0, stream>>>(Wv, S1, NW / 8);
    gemm_nt<2, bf16, bf16><<<gg, 256, 0, stream>>>(S0, S1, bv, S3, Mrows, Dd, Dd, 1.0f);

    conv_bf16<<<gA, 256, 0, stream>>>(k_in, S0, Mrows * Dd / 8);
    conv_bf16<<<gW, 256, 0, stream>>>(Wk, S1 + NW, NW / 8);
    gemm_nt<1, bf16, bf16><<<gg, 256, 0, stream>>>(S0, S1 + NW, bk, S2, Mrows, Dd, Dd, 1.0f);

    conv_bf16<<<gA, 256, 0, stream>>>(q_in, S0, Mrows * Dd / 8);
    gemm_nt<1, float, bf16><<<gg, 256, 0, stream>>>(S0, Wq, bq, S1, Mrows, Dd, Dd, QSC);

    pack_mask<<<(Ls * Ls) / 256, 256, 0, stream>>>(mask, mb);
    attn<<<BHn * (Ls / 128), 512, 0, stream>>>(S1, S2, S3, mb, S0);

    conv_bf16<<<gW, 256, 0, stream>>>(Wo, S2, NW / 8);   // Kp dead after attn
    gemm_nt<0, bf16, float><<<gg, 256, 0, stream>>>(S0, S2, bo, out, Mrows, Dd, Dd, 1.0f);
}